// Round 2
// 746.015 us; speedup vs baseline: 1.0668x; 1.0668x over previous
//
#include <hip/hip_runtime.h>

// GNN_Sine fused, MFMA edition — v3: v2 layout (3 blocks/CU, XOR swizzle,
// feat64 sidecar) with pack2 reverted to v1's manual-RNE (bisect: the
// v_cvt_pk_bf16_f32 inline asm is the prime NaN suspect from v2).
// B=65536, NJ=24, dims 13->64->64->64->65, fp32 in/out.
//
//  * LDS row stride 64 bf16 elems with XOR swizzle (elem ^= (row&7)<<3):
//    buf 49,152 B + 768 B feat64 sidecar -> 3 blocks/CU (v1: 55,296 B, 2).
//    row&7 is lane-constant in both hot phases so the swizzle costs ~0 VALU.
//  * final layer: feat-64 tail stored by lane jq==0 right after the joint's
//    main 256 B chunk (same wave, adjacent in time) -> L2 merges the line;
//    kills the partial-line RMW that inflated WRITE_SIZE 505 MB vs 390 ideal.

#define NJ 24
#define TB 16

typedef __attribute__((ext_vector_type(8))) short bf16x8;
typedef __attribute__((ext_vector_type(4))) float f32x4;

__device__ constexpr int NBR_OFF_C[NJ + 1] = {0,4,7,10,13,16,19,22,25,28,33,35,37,40,43,46,48,51,54,57,60,63,66,68,70};
__device__ constexpr int NBR_LIST_C[70] = {
    0,1,2,3,  0,1,4,  0,2,5,  0,3,6,  1,4,7,  2,5,8,  3,6,9,  4,7,10,
    5,8,11,  6,9,12,13,14,  7,10,  8,11,  9,12,15,  9,13,16,  9,14,17,
    12,15,  13,16,18,  14,17,19,  16,18,20,  17,19,21,  18,20,22,  19,21,23,
    20,22,  21,23
};

__device__ __forceinline__ float bf2f(unsigned short u) {
    return __uint_as_float(((unsigned int)u) << 16);
}
__device__ __forceinline__ unsigned short f2bf(float f) {
    unsigned int u = __float_as_uint(f);
    u += 0x7fffu + ((u >> 16) & 1u);   // RNE
    return (unsigned short)(u >> 16);
}
__device__ __forceinline__ unsigned int pack2(float a, float b) {
    return (unsigned int)f2bf(a) | ((unsigned int)f2bf(b) << 16);
}

// ---------------- weight prepack: fp32 [joint][l][jout] -> bf16 A-fragments ----
// Frag layout: elem = frag*512 + lane*8 + j ; lane holds A[m=lane&15][k=(lane>>4)*8+j]
//   m = jout within Mtile, k = l within ktile (K=32).
// Frag index map: L0 (96): (joint*4+mt)         kt=0   base 0
//                 L1 (192): joint*8+mt*2+kt            base 96
//                 L2 (192):                            base 288
//                 L3 (240): joint*10+mt*2+kt (MT=5)    base 480
__global__ __launch_bounds__(256) void prepack(
    const float* __restrict__ w0, const float* __restrict__ w1,
    const float* __restrict__ w2, const float* __restrict__ w3,
    unsigned short* __restrict__ wp)
{
    const int f = blockIdx.x;
    const int t = threadIdx.x;
    const int lane = t >> 2;
    const int jp = t & 3;

    const float* w; int DIN, DOUT, joint, mt, kt;
    if (f < 96)       { w = w0; DIN = 13; DOUT = 64; int g = f;       joint = g >> 2; mt = g & 3;        kt = 0;     }
    else if (f < 288) { w = w1; DIN = 64; DOUT = 64; int g = f - 96;  joint = g >> 3; mt = (g >> 1) & 3; kt = g & 1; }
    else if (f < 480) { w = w2; DIN = 64; DOUT = 64; int g = f - 288; joint = g >> 3; mt = (g >> 1) & 3; kt = g & 1; }
    else              { w = w3; DIN = 64; DOUT = 65; int g = f - 480; joint = g / 10; int r = g % 10; mt = r >> 1; kt = r & 1; }

    const int jout = mt * 16 + (lane & 15);
    unsigned int packed = 0;
#pragma unroll
    for (int jj = 0; jj < 2; ++jj) {
        const int j = jp * 2 + jj;
        const int l = kt * 32 + (lane >> 4) * 8 + j;
        float v = 0.f;
        if (l < DIN && jout < DOUT) v = w[(joint * DIN + l) * DOUT + jout];
        packed |= (unsigned int)f2bf(v) << (16 * jj);
    }
    *(unsigned int*)(wp + (size_t)f * 512 + lane * 8 + jp * 2) = packed;
}

// ---------------- phase 1: per-joint linear via MFMA --------------------------
// In-place on buf: wave wv owns joints k = wv*6 .. wv*6+5 exclusively, and the
// per-lane ds_reads all precede the ds_writes in program order (wave-lockstep).
template<int KT, int MT>
__device__ __forceinline__ void linear_phase(unsigned short* buf, unsigned short* abuf,
    const unsigned short* __restrict__ wf, int wv, int lane)
{
    const int bl = lane & 15;       // b (N col)
    const int quad = lane >> 4;
    const int sx = (bl & 7) << 3;   // row&7 == bl&7 : lane-constant swizzle
    for (int jj = 0; jj < 6; ++jj) {
        const int k = wv * 6 + jj;
        const int rbase = (k * TB + bl) * 64;
        // B-op: activation fragments (K-contiguous ds_read_b128, swizzled row)
        bf16x8 bfr[KT];
#pragma unroll
        for (int kt = 0; kt < KT; ++kt)
            bfr[kt] = *(bf16x8*)&buf[rbase + ((kt * 32 + quad * 8) ^ sx)];
        // A-op: prepacked weight fragments (coalesced global dwordx4)
        const unsigned short* wj = wf + (size_t)k * (MT * KT * 512) + lane * 8;
        bf16x8 afr[MT][KT];
#pragma unroll
        for (int mt = 0; mt < MT; ++mt)
#pragma unroll
            for (int kt = 0; kt < KT; ++kt)
                afr[mt][kt] = *(const bf16x8*)(wj + (mt * KT + kt) * 512);
        f32x4 acc[MT];
#pragma unroll
        for (int mt = 0; mt < MT; ++mt) {
            acc[mt] = (f32x4){0.f, 0.f, 0.f, 0.f};
#pragma unroll
            for (int kt = 0; kt < KT; ++kt)
                acc[mt] = __builtin_amdgcn_mfma_f32_16x16x32_bf16(afr[mt][kt], bfr[kt], acc[mt], 0, 0, 0);
        }
        // H store: lane holds rows jout = mt*16 + quad*4 .. +3 at col b=bl
        //  -> packed ds_write_b64 back into the same swizzled layout.
        // MT==5: only jout 64 is real -> feat64 sidecar (abuf), quad0 only.
#pragma unroll
        for (int mt = 0; mt < MT; ++mt) {
            if (mt < 4) {
                uint2 p;
                p.x = pack2(acc[mt].x, acc[mt].y);
                p.y = pack2(acc[mt].z, acc[mt].w);
                *(uint2*)&buf[rbase + ((mt * 16 + quad * 4) ^ sx)] = p;
            } else if (quad == 0) {
                abuf[k * TB + bl] = f2bf(acc[mt].x);
            }
        }
    }
}

// ---------------- phase 2: sparse tree aggregation (VALU) ---------------------
template<bool LAST>
__device__ __forceinline__ void agg_phase(unsigned short* buf,
    const unsigned short* abuf,
    const float* __restrict__ aw, const float* __restrict__ bias,
    float* __restrict__ out, int base, int wv, int lane)
{
    const int bsub = lane >> 4;            // 0..3
    const int jq = lane & 15;              // feat quad (4 feats)
    const int b = wv * 4 + bsub;           // 0..15
    const int eo = (jq * 4) ^ ((b & 7) << 3);   // swizzled, lane-constant

    float acc[NJ][4];
#pragma unroll
    for (int n = 0; n < NJ; ++n) {
        acc[n][0] = 0.f; acc[n][1] = 0.f; acc[n][2] = 0.f; acc[n][3] = 0.f;
    }
    const float4 bv = *(const float4*)(bias + jq * 4);

    // read each H row once, scatter-add into compile-time-indexed accumulators
#pragma unroll
    for (int m = 0; m < NJ; ++m) {
        uint2 raw = *(uint2*)&buf[(m * TB + b) * 64 + eo];
        const float h0 = __uint_as_float(raw.x << 16);
        const float h1 = __uint_as_float(raw.x & 0xffff0000u);
        const float h2 = __uint_as_float(raw.y << 16);
        const float h3 = __uint_as_float(raw.y & 0xffff0000u);
#pragma unroll
        for (int e = NBR_OFF_C[m]; e < NBR_OFF_C[m + 1]; ++e) {
            const int n = NBR_LIST_C[e];
            const float c = aw[n * NJ + m];   // uniform -> s_load
            acc[n][0] += c * h0; acc[n][1] += c * h1;
            acc[n][2] += c * h2; acc[n][3] += c * h3;
        }
    }

    if (!LAST) {
#pragma unroll
        for (int n = 0; n < NJ; ++n) {
            const float v0 = fmaxf(acc[n][0] + bv.x, 0.f);
            const float v1 = fmaxf(acc[n][1] + bv.y, 0.f);
            const float v2 = fmaxf(acc[n][2] + bv.z, 0.f);
            const float v3 = fmaxf(acc[n][3] + bv.w, 0.f);
            uint2 p; p.x = pack2(v0, v1); p.y = pack2(v2, v3);
            *(uint2*)&buf[(n * TB + b) * 64 + eo] = p;
        }
    } else {
        const float b64v = bias[64];
        float* ob = out + (size_t)(base + b) * (NJ * 65);
        // feat64 written by lane jq==0 right after joint n's 256 B chunk so the
        // shared L2 line is still resident -> no partial-line RMW eviction.
#pragma unroll
        for (int n = 0; n < NJ; ++n) {
            float* p = ob + n * 65 + jq * 4;
            p[0] = acc[n][0] + bv.x;
            p[1] = acc[n][1] + bv.y;
            p[2] = acc[n][2] + bv.z;
            p[3] = acc[n][3] + bv.w;
            if (jq == 0) {
                float s = b64v;
#pragma unroll
                for (int e = NBR_OFF_C[n]; e < NBR_OFF_C[n + 1]; ++e) {
                    const int m = NBR_LIST_C[e];
                    s += aw[n * NJ + m] * bf2f(abuf[m * TB + b]);
                }
                p[64] = s;
            }
        }
    }
}

// ---------------- main fused kernel -------------------------------------------
__global__ __launch_bounds__(256, 3) void gnn_mfma(
    const float* __restrict__ x, const unsigned short* __restrict__ wp,
    const float* __restrict__ aw0, const float* __restrict__ b0,
    const float* __restrict__ aw1, const float* __restrict__ b1,
    const float* __restrict__ aw2, const float* __restrict__ b2,
    const float* __restrict__ aw3, const float* __restrict__ b3,
    float* __restrict__ out)
{
    __shared__ __align__(16) unsigned short buf[NJ * TB * 64];  // 49,152 B
    __shared__ __align__(8)  unsigned short abuf[NJ * TB];      //    768 B (L3 feat64)

    const int t = threadIdx.x;
    const int lane = t & 63;
    const int wv = t >> 6;
    const int base = blockIdx.x * TB;

    // load x tile -> swizzled [joint][b][feat] bf16, feats 13..31 zeroed (K=32
    // pad), joint 0 masked to zero (mask_root).
    for (int i = t; i < NJ * TB * 16; i += 256) {
        const int k = i >> 8;            // /(16 pairs * 16 b)
        const int b = (i >> 4) & 15;
        const int f2 = (i & 15) * 2;
        float v0 = 0.f, v1 = 0.f;
        if (k > 0) {
            const float* xr = x + (size_t)(base + b) * 312 + k * 13;
            if (f2 < 13)     v0 = xr[f2];
            if (f2 + 1 < 13) v1 = xr[f2 + 1];
        }
        const int row = k * TB + b;
        *(unsigned int*)&buf[row * 64 + (f2 ^ ((row & 7) << 3))] = pack2(v0, v1);
    }
    __syncthreads();

    linear_phase<1, 4>(buf, abuf, wp, wv, lane);                 // L0: K=32(13+pad)
    __syncthreads();
    agg_phase<false>(buf, abuf, aw0, b0, nullptr, base, wv, lane);
    __syncthreads();
    linear_phase<2, 4>(buf, abuf, wp + 96 * 512, wv, lane);      // L1
    __syncthreads();
    agg_phase<false>(buf, abuf, aw1, b1, nullptr, base, wv, lane);
    __syncthreads();
    linear_phase<2, 4>(buf, abuf, wp + 288 * 512, wv, lane);     // L2
    __syncthreads();
    agg_phase<false>(buf, abuf, aw2, b2, nullptr, base, wv, lane);
    __syncthreads();
    linear_phase<2, 5>(buf, abuf, wp + 480 * 512, wv, lane);     // L3: MT=5 (65 cols)
    __syncthreads();
    agg_phase<true>(buf, abuf, aw3, b3, out, base, wv, lane);
}

extern "C" void kernel_launch(void* const* d_in, const int* in_sizes, int n_in,
                              void* d_out, int out_size, void* d_ws, size_t ws_size,
                              hipStream_t stream)
{
    const float* x   = (const float*)d_in[0];
    const float* w0  = (const float*)d_in[1];
    const float* aw0 = (const float*)d_in[2];
    const float* b0  = (const float*)d_in[3];
    const float* w1  = (const float*)d_in[4];
    const float* aw1 = (const float*)d_in[5];
    const float* b1  = (const float*)d_in[6];
    const float* w2  = (const float*)d_in[7];
    const float* aw2 = (const float*)d_in[8];
    const float* b2  = (const float*)d_in[9];
    const float* w3  = (const float*)d_in[10];
    const float* aw3 = (const float*)d_in[11];
    const float* b3  = (const float*)d_in[12];
    float* out = (float*)d_out;
    unsigned short* wp = (unsigned short*)d_ws;   // needs 737,280 B (720 frags * 1 KB)

    prepack<<<720, 256, 0, stream>>>(w0, w1, w2, w3, wp);

    const int blocks = 65536 / TB;   // 4096
    gnn_mfma<<<blocks, 256, 0, stream>>>(x, wp, aw0, b0, aw1, b1,
                                         aw2, b2, aw3, b3, out);
}